// Round 11
// baseline (308.655 us; speedup 1.0000x reference)
//
#include <hip/hip_runtime.h>
#include <hip/hip_fp16.h>
#include <math.h>

#define BB 8
#define CC 64
#define HH 128
#define WW 128
#define HO 64
#define WO 128
#define OC 64
#define HW (HH * WW)
#define NBLOCKS 1024u

typedef __attribute__((ext_vector_type(4))) float floatx4;
typedef __attribute__((ext_vector_type(8))) _Float16 half8;

__device__ __forceinline__ unsigned short f2h(float f) {
    __half h = __float2half(f);
    return __builtin_bit_cast(unsigned short, h);
}
__device__ __forceinline__ unsigned int packpair(float a, float b) {
    __half2 h = __floats2half2_rn(a, b);   // lo=a hi=b
    return __builtin_bit_cast(unsigned int, h);
}
// Barrier that drains ONLY LDS ops: global loads stay in flight across it.
__device__ __forceinline__ void lgkm_barrier() {
    asm volatile("s_waitcnt lgkmcnt(0)" ::: "memory");
    __builtin_amdgcn_s_barrier();
}
// Hand-rolled grid barrier (R10's hipLaunchCooperativeKernel never executed —
// unchecked launch error, output untouched). Co-residency by construction:
// LDS 18.4KB -> 8/CU; launch_bounds(256,4) -> <=128 VGPR -> 4 blocks/CU;
// grid 1024 = 4 x 256 CU. Counter zeroed per replay via hipMemsetAsync.
// Bounded spin: a co-residency surprise degrades to wrong-answer, not hang.
__device__ __forceinline__ void grid_sync(unsigned* cnt) {
    __syncthreads();
    if (threadIdx.x == 0) {
        __threadfence();                       // device-scope release (wb L2)
        atomicAdd(cnt, 1u);
        unsigned guard = 0;
        while (atomicAdd(cnt, 0u) < NBLOCKS && guard < (1u << 24)) {
            __builtin_amdgcn_s_sleep(8);
            ++guard;
        }
    }
    __syncthreads();
    __threadfence();                           // device-scope acquire (inv)
}

// ---------------------------------------------------------------------------
// ONE kernel: prep phase -> hand grid barrier -> fused phase.
// PREP (proven R5 code): block i -> weight chunk (i<216) + BOTH w-half
// transpose slabs of row (b=i&7, y=i>>3) -> xP pair-packed fp16.
// FUSED (proven R3 schedule): block i = (b=i&7, h, wt2) runs two 32-pos
// tiles. b in LOW bits both phases -> XCD-affine xP (dirty-L2 hits).
// ---------------------------------------------------------------------------
__global__ __launch_bounds__(256, 4) void merged(
    const float* __restrict__ x,
    const float* __restrict__ w_off, const float* __restrict__ w_msk,
    const float* __restrict__ w_conv,
    const float* __restrict__ b_off, const float* __restrict__ b_msk,
    unsigned int* __restrict__ xP,
    unsigned short* __restrict__ Wom, unsigned short* __restrict__ W2,
    unsigned* __restrict__ syncnt,
    float* __restrict__ out)
{
    __shared__ __align__(16) char lds[18432];
    int tid = threadIdx.x;
    int i = blockIdx.x;                // 1024 blocks

    // ================= PREP PHASE =================
    if (i < 72) {
        int u = i * 256 + tid;               // < 18432 = 32*576
        int chn = u / 576, kk = u % 576;
        int xs = kk >> 6, cc = kk & 63;
        float v = 0.0f;
        if (chn < 18)      v = w_off[(chn * CC + cc) * 9 + xs];
        else if (chn < 27) v = w_msk[((chn - 18) * CC + cc) * 9 + xs];
        Wom[u] = f2h(v);
    } else if (i < 216) {
        int u = (i - 72) * 256 + tid;        // < 36864
        int k = u % 9, cc = (u / 9) % CC, o = u / (CC * 9);
        W2[((size_t)k * OC + o) * CC + cc] = f2h(w_conv[u]);
    }

    // transpose: both w-halves of row (bs, y)  [R5 prep, 2 slabs/block]
    {
        float (*T)[65] = (float(*)[65])lds;  // [w 0..64][c], stride 65
        int bs = i & 7, y = i >> 3;
#pragma unroll 1
        for (int j = 0; j < 2; ++j) {
            __syncthreads();                 // T reuse across slabs
            int w0 = j << 6;
            const float* xb = x + (((size_t)bs * CC) * HH + y) * WW + w0;
#pragma unroll
            for (int it = 0; it < 4; ++it) {
                int idx = it * 256 + tid;            // 0..1023
                int cch = idx >> 4, f4 = (idx & 15) << 2;
                floatx4 v = *(const floatx4*)(xb + (size_t)cch * HW + f4);
                T[f4 + 0][cch] = v.x;
                T[f4 + 1][cch] = v.y;
                T[f4 + 2][cch] = v.z;
                T[f4 + 3][cch] = v.w;
            }
            if (tid < 64) {
                float e = 0.0f;
                if (w0 + 64 < WW) e = xb[(size_t)tid * HW + 64];
                T[64][tid] = e;
            }
            __syncthreads();
            int c4 = tid & 15;               // channel block (4c4..4c4+3)
            int wr = tid >> 4;               // 0..15
            size_t rowbase = (((size_t)bs * HH + y) * WW) + w0;
#pragma unroll
            for (int jj = 0; jj < 4; ++jj) {
                int w = 16 * jj + wr;
                floatx4 a  = *(const floatx4*)&T[w][4 * c4];
                floatx4 bb = *(const floatx4*)&T[w + 1][4 * c4];
                uint4 d;
                d.x = packpair(a.x, bb.x);
                d.y = packpair(a.y, bb.y);
                d.z = packpair(a.z, bb.z);
                d.w = packpair(a.w, bb.w);
                *(uint4*)(xP + (rowbase + w) * 64 + 4 * c4) = d;
            }
        }
    }

    // ================= GRID SYNC =================
    grid_sync(syncnt);                       // xP/Wom/W2 visible device-wide

    // ================= FUSED PHASE =================
    typedef _Float16 XsRow[34][72];
    XsRow* Xs = (XsRow*)lds;                                        // [3][34][72]
    unsigned short (*S)[32][64] = (unsigned short(*)[32][64])lds;   // [2][32][64]
    uint2* metaC = (uint2*)(lds + 8192);                            // 288*8
    uint2* metaR = (uint2*)(lds + 10496);                           // 288*8
    float (*omr)[33] = (float(*)[33])(lds + 14720);                 // [27][33]

    int lane = tid & 63;
    int wv = __builtin_amdgcn_readfirstlane(tid >> 6);
    int b = i & 7;                     // XCD-affine (plane b on XCD b)
    int rest = i >> 3;                 // 0..127
    int h = rest >> 1;
    int wt2 = rest & 1;
    int h2 = 2 * h - 1;
    int m16 = lane & 15, q = lane >> 4;

    const unsigned int* xPb_u = xP + (size_t)b * HW * 64;
    const char* xPb = (const char*)xPb_u;
    unsigned int voff = 4u * (unsigned)lane;

#pragma unroll 1
    for (int t2 = 0; t2 < 2; ++t2) {
        int w0 = (wt2 * 2 + t2) * 32;
        lgkm_barrier();                // prior tile's S reads done before Xs overwrite

        // ---- phase 1: stage slab from xP pair-lows (uint4 coalesced) ----
        for (int u = tid; u < 1632; u += 256) {      // 1632 = 3*34*16
            int ky = u / 544;
            int rem = u - ky * 544;
            int col = rem >> 4, c4 = rem & 15;
            int hy = h2 + ky, wc = w0 - 1 + col;
            unsigned int lo0 = 0u, lo1 = 0u;
            if ((unsigned)hy < (unsigned)HH && (unsigned)wc < (unsigned)WW) {
                const uint4 g = *(const uint4*)(xPb_u + ((size_t)hy * WW + wc) * 64 + c4 * 4);
                lo0 = (g.x & 0xffffu) | (g.y << 16);
                lo1 = (g.z & 0xffffu) | (g.w << 16);
            }
            uint2* dst = (uint2*)((unsigned short*)lds + ((ky * 34 + col) * 72 + c4 * 4));
            *dst = make_uint2(lo0, lo1);
        }
        lgkm_barrier();

        // ---- phase 2: om GEMM (wave = 2 Mtiles x 2 Ntiles, K=576) ----
        {
            int mt = wv & 1, nt = wv >> 1;
            floatx4 a = (floatx4){0.f, 0.f, 0.f, 0.f};
            const _Float16* wa = (const _Float16*)Wom + (mt * 16 + m16) * 576 + q * 8;
#pragma unroll
            for (int t = 0; t < 18; ++t) {
                int xs = t >> 1, ky = xs / 3, kx = xs % 3;
                half8 af = *(const half8*)(wa + t * 32);
                half8 bf = *(const half8*)&Xs[ky][nt * 16 + m16 + kx][(t & 1) * 32 + q * 8];
                a = __builtin_amdgcn_mfma_f32_16x16x32_f16(af, bf, a, 0, 0, 0);
            }
#pragma unroll
            for (int r = 0; r < 4; ++r) {
                int chn = mt * 16 + q * 4 + r;
                if (chn < 27) omr[chn][nt * 16 + m16] = a[r];
            }
        }
        lgkm_barrier();   // omr ready; Xs reads done (meta/S may overlay)

        // ---- phase 3: coeffs (half2) + packed row byte-offsets ----
        for (int u = tid; u < 288; u += 256) {
            int kk = u >> 5, pos = u & 31;
            float offy = omr[2 * kk][pos] + b_off[2 * kk];
            float offx = omr[2 * kk + 1][pos] + b_off[2 * kk + 1];
            float mk = 1.0f / (1.0f + __expf(-(omr[18 + kk][pos] + b_msk[kk])));
            float py = offy + (float)(kk / 3) + (float)h2;
            float px = offx + (float)(kk % 3) + (float)(w0 + pos - 1);

            float y0f = floorf(py), x0f = floorf(px);
            float dy = py - y0f, dx = px - x0f;
            int y0 = (int)y0f, x0 = (int)x0f;
            int y1 = y0 + 1, x1 = x0 + 1;
            bool vy0 = (unsigned)y0 < (unsigned)HH;
            bool vy1 = (unsigned)y1 < (unsigned)HH;
            bool vx0 = (unsigned)x0 < (unsigned)WW;
            bool vx1 = (unsigned)x1 < (unsigned)WW;
            float w00 = (1.0f - dy) * (1.0f - dx) * ((vy0 && vx0) ? mk : 0.0f);
            float w01 = (1.0f - dy) * dx          * ((vy0 && vx1) ? mk : 0.0f);
            float w10 = dy * (1.0f - dx)          * ((vy1 && vx0) ? mk : 0.0f);
            float w11 = dy * dx                   * ((vy1 && vx1) ? mk : 0.0f);
            int xbase = min(max(x0, 0), WW - 2);
            bool s0 = x0 > xbase;
            bool s1 = x1 > xbase;
            float cxA = (s0 ? 0.f : w00) + (s1 ? 0.f : w01);
            float cyA = (s0 ? w00 : 0.f) + (s1 ? w01 : 0.f);
            float cxB = (s0 ? 0.f : w10) + (s1 ? 0.f : w11);
            float cyB = (s0 ? w10 : 0.f) + (s1 ? w11 : 0.f);
            int yc0 = min(max(y0, 0), HH - 1);
            int yc1 = min(max(y1, 0), HH - 1);

            __half2 hA = __floats2half2_rn(cxA, cyA);
            __half2 hB = __floats2half2_rn(cxB, cyB);
            metaC[u] = make_uint2(__builtin_bit_cast(unsigned int, hA),
                                  __builtin_bit_cast(unsigned int, hB));
            metaR[u] = make_uint2((unsigned)(yc0 * WW + xbase) * 256u,
                                  (unsigned)(yc1 * WW + xbase) * 256u);
        }
        lgkm_barrier();

        // ---- phase 4: depth-2 pipelined sampling + main MFMA ----
        int p0 = wv * 8;               // my 8 positions
        floatx4 acc0 = (floatx4){0.f, 0.f, 0.f, 0.f};
        floatx4 acc1 = (floatx4){0.f, 0.f, 0.f, 0.f};

        unsigned int Ga0[8], Ga1[8], Gb0[8], Gb1[8];
        half8 afr[3][2];               // rotating W2 prefetch, 2 taps ahead
        const _Float16* W2w = (const _Float16*)W2 + ((size_t)wv * 16 + m16) * CC + q * 8;

        auto loadaf = [&](int k, int slot) {
#pragma unroll
            for (int s = 0; s < 2; ++s)
                afr[slot][s] = *(const half8*)(W2w + (size_t)k * (OC * CC) + s * 32);
        };
        auto issue = [&](int k, unsigned int (&A0)[8], unsigned int (&A1)[8]) {
#pragma unroll
            for (int ii = 0; ii < 8; ++ii) {
                uint2 zw = metaR[k * 32 + p0 + ii];      // broadcast ds_read
                const char* r0 = xPb + (unsigned)__builtin_amdgcn_readfirstlane((int)zw.x);
                const char* r1 = xPb + (unsigned)__builtin_amdgcn_readfirstlane((int)zw.y);
                A0[ii] = *(const unsigned int*)(r0 + voff);
                A1[ii] = *(const unsigned int*)(r1 + voff);
            }
        };
        auto dostore = [&](int k, int buf, unsigned int (&A0)[8], unsigned int (&A1)[8]) {
#pragma unroll
            for (int ii = 0; ii < 8; ++ii) {
                uint2 cf = metaC[k * 32 + p0 + ii];      // broadcast ds_read
                __half2 hA = __builtin_bit_cast(__half2, cf.x);
                __half2 hB = __builtin_bit_cast(__half2, cf.y);
                __half2 g0 = __builtin_bit_cast(__half2, A0[ii]);
                __half2 g1 = __builtin_bit_cast(__half2, A1[ii]);
                __half2 p = __hfma2(hA, g0, __hmul2(hB, g1));   // v_pk_fma_f16
                __half sv = __hadd(__low2half(p), __high2half(p));
                int pos = p0 + ii;
                S[buf][pos][((lane >> 3) ^ (pos & 7)) * 8 + (lane & 7)] =
                    __builtin_bit_cast(unsigned short, sv);
            }
        };
        auto mfma_step = [&](int k, int buf, int slot) {
#pragma unroll
            for (int s = 0; s < 2; ++s) {
                half8 af = afr[slot][s];
                int cb = ((q + 4 * s) ^ (m16 & 7)) * 8;
                half8 bf0 = *(const half8*)&S[buf][m16][cb];
                half8 bf1 = *(const half8*)&S[buf][16 + m16][cb];
                acc0 = __builtin_amdgcn_mfma_f32_16x16x32_f16(af, bf0, acc0, 0, 0, 0);
                acc1 = __builtin_amdgcn_mfma_f32_16x16x32_f16(af, bf1, acc1, 0, 0, 0);
            }
        };

        // prologue. vmem FIFO: af(0) af(1) G(0) [wait G(0) retires afs] G(1)
        loadaf(0, 0);
        loadaf(1, 1);
        issue(0, Ga0, Ga1);
        dostore(0, 0, Ga0, Ga1);
        issue(1, Gb0, Gb1);
#pragma unroll
        for (int k = 0; k < 9; ++k) {
            lgkm_barrier();            // S[k&1] visible; gathers keep flying
            if (k < 7) {
                loadaf(k + 2, (k + 2) % 3);          // af ahead of its G
                if ((k & 1) == 0) issue(k + 2, Ga0, Ga1);
                else              issue(k + 2, Gb0, Gb1);
            }
            mfma_step(k, k & 1, k % 3);              // no vmem wait here
            if (k < 8) {
                if ((k & 1) == 0) dostore(k + 1, 1, Gb0, Gb1);
                else              dostore(k + 1, 0, Ga0, Ga1);
            }
        }

        // epilogue: C/D col=lane&15 (pos), row=(lane>>4)*4+reg (o)
#pragma unroll
        for (int nt = 0; nt < 2; ++nt) {
            floatx4 av = nt ? acc1 : acc0;
#pragma unroll
            for (int r = 0; r < 4; ++r) {
                int o = wv * 16 + q * 4 + r;
                out[(((size_t)b * OC + o) * HO + h) * WO + w0 + nt * 16 + m16] = av[r];
            }
        }
    }
}

// ---------------------------------------------------------------------------
extern "C" void kernel_launch(void* const* d_in, const int* in_sizes, int n_in,
                              void* d_out, int out_size, void* d_ws, size_t ws_size,
                              hipStream_t stream)
{
    const float* x      = (const float*)d_in[0];
    const float* w_off  = (const float*)d_in[1];
    const float* b_off  = (const float*)d_in[2];
    const float* w_msk  = (const float*)d_in[3];
    const float* b_msk  = (const float*)d_in[4];
    const float* w_conv = (const float*)d_in[5];
    float* out = (float*)d_out;

    // workspace: xP (33.55 MB) | Wom (36.9 KB) | W2 (73.7 KB) | sync counter
    unsigned int* xP = (unsigned int*)d_ws;                       // 8*HW*64 * 4B
    unsigned short* Wom = (unsigned short*)(xP + (size_t)BB * HW * 64); // 32*576
    unsigned short* W2 = Wom + 32 * 576;                          // 36864
    unsigned* syncnt = (unsigned*)((char*)(W2 + 36864));          // 64B, aligned

    hipMemsetAsync(syncnt, 0, 64, stream);   // reset barrier each replay
    merged<<<dim3(NBLOCKS), dim3(256), 0, stream>>>(
        x, w_off, w_msk, w_conv, b_off, b_msk, xP, Wom, W2, syncnt, out);
}